// Round 8
// baseline (143.091 us; speedup 1.0000x reference)
//
#include <hip/hip_runtime.h>

// SimpleSNN: T=16, B=4096, N_IN=784, N_HID=256, N_OUT=10
// gemm1 path redesigned around exact i8 arithmetic:
//   conv_x  : X fp32 {0,1} -> Xq i8, K padded 784->832 (13*64)
//   conv_w3 : W1 -> 3 i8 planes with power-of-2 scales
//             w = 2^-11*a + 2^-18*b + 2^-25*c  (residual <= 2^-26, tighter
//             than the previously-passing bf16 hi/lo split; i32 acc exact)
//   gemm1_i8: block = 32 cols x 256 rows; ALL W for the block's cols lives
//             in LDS (78 KB, loaded once) -> ZERO barriers in k-loop.
//             A streams global->reg (ping-pong prefetch), 24 MFMA/step.
//   lif1 / gemm2_f32 / lif2 unchanged (verified exact).

#define T_STEPS 16
#define B_SZ    4096
#define N_IN    784
#define N_HID   256
#define N_OUT   10
#define M_TOT   (T_STEPS * B_SZ)   // 65536
#define KP8     832                // 13 * 64
#define NSTEP   13                 // K=64 steps
#define WPLANE  (N_HID * KP8)      // i8 elems per W plane

typedef int    i32x4 __attribute__((ext_vector_type(4)));
typedef unsigned int u32;
typedef unsigned char u8;

#define GLOAD_LDS(SRC, DST) \
    __builtin_amdgcn_global_load_lds( \
        (const __attribute__((address_space(1))) void*)(SRC), \
        (__attribute__((address_space(3))) void*)(DST), 16, 0, 0)

// ---------------- conv_x: fp32 {0,1} -> i8, pad K 784->832 -----------------
__global__ __launch_bounds__(256) void conv_x(
    const float* __restrict__ X, u8* __restrict__ Xq)
{
    // one thread = one 16-byte output slot; 52 slots per row, slots 49..51 zero
    const long idx = (long)blockIdx.x * 256 + threadIdx.x;   // < 65536*52
    const long m = idx / 52;
    const int  s = (int)(idx - m * 52);
    uint4 o = make_uint4(0u, 0u, 0u, 0u);
    if (s < 49) {                                  // 49*16 = 784 exactly
        const uint4* src = reinterpret_cast<const uint4*>(X + m * N_IN + s * 16);
        const uint4 f0 = src[0], f1 = src[1], f2 = src[2], f3 = src[3];
        auto pk = [](uint4 f) -> u32 {
            return (f.x ? 1u : 0u) | ((f.y ? 1u : 0u) << 8) |
                   ((f.z ? 1u : 0u) << 16) | ((f.w ? 1u : 0u) << 24);
        };
        o.x = pk(f0); o.y = pk(f1); o.z = pk(f2); o.w = pk(f3);
    }
    reinterpret_cast<uint4*>(Xq)[idx] = o;
}

// ---------------- conv_w3: W1 -> 3 i8 planes (power-of-2 scales) -----------
__global__ __launch_bounds__(256) void conv_w3(
    const float* __restrict__ W1, char* __restrict__ Wq)
{
    const int idx = blockIdx.x * 256 + threadIdx.x;   // over 256*832
    if (idx >= N_HID * KP8) return;
    const int n = idx / KP8, k = idx % KP8;
    const float w = (k < N_IN) ? W1[n * N_IN + k] : 0.0f;
    const float a = rintf(w * 2048.0f);                       // s1 = 2^-11
    const float r1 = fmaf(a, -4.8828125e-4f, w);
    const float b = rintf(r1 * 262144.0f);                    // s2 = 2^-18
    const float r2 = fmaf(b, -3.814697265625e-6f, r1);
    const float c = rintf(r2 * 33554432.0f);                  // s3 = 2^-25
    Wq[idx]              = (char)(int)a;
    Wq[WPLANE + idx]     = (char)(int)b;
    Wq[2 * WPLANE + idx] = (char)(int)c;
}

// ---------------- gemm1_i8 --------------------------------------------------
__global__ __launch_bounds__(256, 2) void gemm1_i8(
    const u8* __restrict__ Xq,
    const u8* __restrict__ Wq,
    const float* __restrict__ b1,
    float* __restrict__ C)
{
    // B LDS: [plane][32 rows][832]; 16B slot sp holds source slot
    // (sp&~3) | ((sp&3)^(row&3))  -> <=4-way bank conflict on b128 reads
    __shared__ u8 Bq[3 * 32 * KP8];   // 79,872 B -> 2 blocks/CU

    const int tid  = threadIdx.x;
    const int lane = tid & 63;
    const int w    = tid >> 6;          // wave 0..3: m-chunk w*64
    // grid 2048 = 256 m-tiles x 8 n-slices; bid bits [2:0]=mt_lo, [5:3]=ns,
    // [10:6]=mt_hi -> the 8 n-slices of one m-panel land on ONE XCD (L2 reuse)
    const int bid = blockIdx.x;
    const int mt  = (bid & 7) | ((bid >> 6) << 3);
    const int ns  = (bid >> 3) & 7;
    const int m0  = mt * 256;
    const int n0  = ns * 32;
    const int ls  = lane >> 4;          // k-slice 0..3 (16 bytes each)
    const int lr  = lane & 15;

    // ---- load W planes into LDS once (source-swizzled, dest linear) ----
    {
        const int nIt = (w < 2) ? 20 : 19;          // 4992 units / 256 thr
        for (int it = 0; it < nIt; ++it) {
            const int u     = it * 256 + tid;
            const int plane = u / 1664;
            const int rem   = u - plane * 1664;
            const int row   = rem / 52;
            const int sp    = rem - row * 52;
            const int sl    = (sp & ~3) | ((sp & 3) ^ (row & 3));
            const u8* src = Wq + (size_t)plane * WPLANE +
                            (size_t)(n0 + row) * KP8 + sl * 16;
            GLOAD_LDS(src, &Bq[u * 16]);
        }
    }
    __syncthreads();                    // the ONLY barrier in this kernel

    // ---- A pointers: wave-owned 64 rows, fragment i = 16 rows ----
    const u8* aP[4];
    #pragma unroll
    for (int i = 0; i < 4; ++i)
        aP[i] = Xq + (size_t)(m0 + w * 64 + i * 16 + lr) * KP8 + ls * 16;

    // ---- B byte offsets per (j,p); step adds s*64 ----
    int bOff[2][3];
    #pragma unroll
    for (int j = 0; j < 2; ++j) {
        const int row = j * 16 + lr;
        #pragma unroll
        for (int p = 0; p < 3; ++p)
            bOff[j][p] = p * (32 * KP8) + row * KP8 + ((ls ^ (row & 3)) << 4);
    }

    i32x4 acc[4][2][3];
    #pragma unroll
    for (int i = 0; i < 4; ++i)
        #pragma unroll
        for (int j = 0; j < 2; ++j)
            #pragma unroll
            for (int p = 0; p < 3; ++p)
                acc[i][j][p] = (i32x4){0, 0, 0, 0};

    auto mmstep = [&](const uint4* af, int s) {
        uint4 bf[2][3];
        #pragma unroll
        for (int j = 0; j < 2; ++j)
            #pragma unroll
            for (int p = 0; p < 3; ++p)
                bf[j][p] = *reinterpret_cast<const uint4*>(&Bq[bOff[j][p] + s * 64]);
        #pragma unroll
        for (int i = 0; i < 4; ++i)
            #pragma unroll
            for (int j = 0; j < 2; ++j)
                #pragma unroll
                for (int p = 0; p < 3; ++p)
                    acc[i][j][p] = __builtin_amdgcn_mfma_i32_16x16x64_i8(
                        __builtin_bit_cast(i32x4, af[i]),
                        __builtin_bit_cast(i32x4, bf[j][p]),
                        acc[i][j][p], 0, 0, 0);
    };

    // ---- barrier-free k-loop: manual ping-pong A prefetch ----
    uint4 afA[4], afB[4];
    #pragma unroll
    for (int i = 0; i < 4; ++i)
        afA[i] = *reinterpret_cast<const uint4*>(aP[i]);          // step 0

    for (int s = 0; s < 12; s += 2) {
        #pragma unroll
        for (int i = 0; i < 4; ++i)                               // prefetch s+1
            afB[i] = *reinterpret_cast<const uint4*>(aP[i] + (s + 1) * 64);
        mmstep(afA, s);
        #pragma unroll
        for (int i = 0; i < 4; ++i)                               // prefetch s+2
            afA[i] = *reinterpret_cast<const uint4*>(aP[i] + (s + 2) * 64);
        mmstep(afB, s + 1);
    }
    mmstep(afA, 12);                                              // final step

    // ---- epilogue: c1 = b1 + 2^-11*A1 + 2^-18*A2 + 2^-25*A3 ----
    const float s1 = 4.8828125e-4f;          // 2^-11
    const float s2 = 3.814697265625e-6f;     // 2^-18
    const float s3 = 2.9802322387695312e-8f; // 2^-25
    #pragma unroll
    for (int j = 0; j < 2; ++j) {
        const int col  = n0 + j * 16 + lr;
        const float bb = b1[col];
        #pragma unroll
        for (int i = 0; i < 4; ++i) {
            const int rbase = m0 + w * 64 + i * 16 + (ls << 2);
            #pragma unroll
            for (int q = 0; q < 4; ++q) {
                const float v = fmaf(s1, (float)acc[i][j][0][q],
                                fmaf(s2, (float)acc[i][j][1][q],
                                fmaf(s3, (float)acc[i][j][2][q], bb)));
                C[(size_t)(rbase + q) * N_HID + col] = v;
            }
        }
    }
}

// ---------------- LIF1: per (b,n), loop t; overwrite C1 with z1 ------------
__global__ __launch_bounds__(256) void lif1_kernel(float* __restrict__ C1)
{
    const int g = blockIdx.x * 256 + threadIdx.x;
    const size_t stride = (size_t)B_SZ * N_HID;
    float v = 0.0f, cur = 0.0f;
    #pragma unroll
    for (int t = 0; t < T_STEPS; ++t) {
        const size_t off = (size_t)t * stride + g;
        const float c = C1[off];
        const float vd = v + 0.1f * ((0.0f - v) + cur);
        const float id = cur - 0.2f * cur;
        const bool  sp = vd > 1.0f;
        C1[off] = sp ? 1.0f : 0.0f;
        v = sp ? 0.0f : vd;
        cur = id + c;
    }
}

// ---------------- GEMM2: M=65536, K=256, N=10; 64 rows/block, 640 thr ------
__global__ __launch_bounds__(640) void gemm2_f32(
    const float* __restrict__ Z, const float* __restrict__ W2,
    const float* __restrict__ b2, float* __restrict__ C2)
{
    __shared__ float zs[64 * 268];
    __shared__ float ws[N_OUT * N_HID];
    const int tid = threadIdx.x;
    const int m0 = blockIdx.x * 64;

    for (int idx = tid; idx < 4096; idx += 640) {
        const int r = idx >> 6;
        const int c = (idx & 63) << 2;
        *(float4*)&zs[r * 268 + c] =
            *(const float4*)&Z[(size_t)(m0 + r) * N_HID + c];
    }
    *(float4*)&ws[tid * 4] = *(const float4*)&W2[tid * 4];
    __syncthreads();

    const int o = tid >> 6;
    const int r = tid & 63;
    float acc = b2[o];
    #pragma unroll
    for (int k = 0; k < N_HID; k += 4) {
        const float4 z4 = *(const float4*)&zs[r * 268 + k];
        const float4 w4 = *(const float4*)&ws[o * N_HID + k];
        acc += z4.x * w4.x + z4.y * w4.y + z4.z * w4.z + z4.w * w4.w;
    }
    C2[(size_t)(m0 + r) * N_OUT + o] = acc;
}

// ---------------- LIF2: per (b,o), loop t; accumulate spike count ----------
__global__ __launch_bounds__(256) void lif2_kernel(
    const float* __restrict__ C2, float* __restrict__ out)
{
    const int g = blockIdx.x * 256 + threadIdx.x;
    const int stride = B_SZ * N_OUT;
    float v = 0.0f, cur = 0.0f, s = 0.0f;
    #pragma unroll
    for (int t = 0; t < T_STEPS; ++t) {
        const float c = C2[t * stride + g];
        const float vd = v + 0.1f * ((0.0f - v) + cur);
        const float id = cur - 0.2f * cur;
        const bool  sp = vd > 1.0f;
        s += sp ? 1.0f : 0.0f;
        v = sp ? 0.0f : vd;
        cur = id + c;
    }
    out[g] = s;
}

extern "C" void kernel_launch(void* const* d_in, const int* in_sizes, int n_in,
                              void* d_out, int out_size, void* d_ws, size_t ws_size,
                              hipStream_t stream)
{
    const float* X  = (const float*)d_in[0];
    const float* W1 = (const float*)d_in[1];
    const float* b1 = (const float*)d_in[2];
    const float* W2 = (const float*)d_in[3];
    const float* b2 = (const float*)d_in[4];
    float* out = (float*)d_out;

    // ws layout: [Wq 0.64MB][pad->1MB][Xq 54.5MB][C1 67MB][C2 2.6MB] ~120MB
    char* Wq = (char*)d_ws;
    u8*   Xq = (u8*)d_ws + (1 << 20);
    float* C1 = (float*)((char*)d_ws + (1 << 20) + (size_t)M_TOT * KP8);
    float* C2 = C1 + (size_t)M_TOT * N_HID;

    conv_x<<<(M_TOT * (KP8 / 16)) / 256, 256, 0, stream>>>(X, Xq);

    conv_w3<<<(N_HID * KP8) / 256, 256, 0, stream>>>(W1, Wq);

    gemm1_i8<<<2048, 256, 0, stream>>>(Xq, (const u8*)Wq, b1, C1);

    lif1_kernel<<<(B_SZ * N_HID) / 256, 256, 0, stream>>>(C1);

    gemm2_f32<<<M_TOT / 64, 640, 0, stream>>>(C1, W2, b2, C2);

    lif2_kernel<<<(B_SZ * N_OUT) / 256, 256, 0, stream>>>(C2, out);
}

// Round 9
// 131.137 us; speedup vs baseline: 1.0912x; 1.0912x over previous
//
#include <hip/hip_runtime.h>

// SimpleSNN: T=16, B=4096, N_IN=784, N_HID=256, N_OUT=10
//   conv_x      : X fp32 {0,1} -> Xq i8, K padded 784->832
//   conv_w3     : W1 -> 3 i8 planes, w = 2^-11 a + 2^-18 b + 2^-25 c (exact-ish,
//                 residual <= 2^-26; i32 MFMA accumulation exact) [round-8-verified]
//   gemm1_lif1  : FUSED. Block = 128 b-rows x 16 cols, loops t=0..15 with LIF
//                 state (v,cur) in registers; writes z1 as i8 only.
//                 W (3 planes x 16 cols) in LDS once, padded rows -> no barriers
//                 in the t/k loops. Same MFMA order + epilogue math as round 8.
//   gemm2_f32   : reads z1 i8 -> fp32 (exact), identical dot -> bitwise layer-2
//   lif2        : unchanged

#define T_STEPS 16
#define B_SZ    4096
#define N_IN    784
#define N_HID   256
#define N_OUT   10
#define M_TOT   (T_STEPS * B_SZ)   // 65536
#define KP8     832                // 13 * 64
#define WPLANE  (N_HID * KP8)      // i8 elems per W plane
#define WROW    848                // padded LDS row stride (53*16): 2-way banks only
#define WPL     (16 * WROW)        // per-plane LDS bytes (13568)

typedef int    i32x4 __attribute__((ext_vector_type(4)));
typedef unsigned int u32;
typedef unsigned char u8;

// ---------------- conv_x: fp32 {0,1} -> i8, pad K 784->832 -----------------
__global__ __launch_bounds__(256) void conv_x(
    const float* __restrict__ X, u8* __restrict__ Xq)
{
    const long idx = (long)blockIdx.x * 256 + threadIdx.x;   // < 65536*52
    const long m = idx / 52;
    const int  s = (int)(idx - m * 52);
    uint4 o = make_uint4(0u, 0u, 0u, 0u);
    if (s < 49) {                                  // 49*16 = 784 exactly
        const uint4* src = reinterpret_cast<const uint4*>(X + m * N_IN + s * 16);
        const uint4 f0 = src[0], f1 = src[1], f2 = src[2], f3 = src[3];
        auto pk = [](uint4 f) -> u32 {
            return (f.x ? 1u : 0u) | ((f.y ? 1u : 0u) << 8) |
                   ((f.z ? 1u : 0u) << 16) | ((f.w ? 1u : 0u) << 24);
        };
        o.x = pk(f0); o.y = pk(f1); o.z = pk(f2); o.w = pk(f3);
    }
    reinterpret_cast<uint4*>(Xq)[idx] = o;
}

// ---------------- conv_w3: W1 -> 3 i8 planes (power-of-2 scales) -----------
__global__ __launch_bounds__(256) void conv_w3(
    const float* __restrict__ W1, char* __restrict__ Wq)
{
    const int idx = blockIdx.x * 256 + threadIdx.x;   // over 256*832
    if (idx >= N_HID * KP8) return;
    const int n = idx / KP8, k = idx % KP8;
    const float w = (k < N_IN) ? W1[n * N_IN + k] : 0.0f;
    const float a = rintf(w * 2048.0f);                       // s1 = 2^-11
    const float r1 = fmaf(a, -4.8828125e-4f, w);
    const float b = rintf(r1 * 262144.0f);                    // s2 = 2^-18
    const float r2 = fmaf(b, -3.814697265625e-6f, r1);
    const float c = rintf(r2 * 33554432.0f);                  // s3 = 2^-25
    Wq[idx]              = (char)(int)a;
    Wq[WPLANE + idx]     = (char)(int)b;
    Wq[2 * WPLANE + idx] = (char)(int)c;
}

// ---------------- gemm1 + lif1 fused ---------------------------------------
__global__ __launch_bounds__(256, 2) void gemm1_lif1(
    const u8* __restrict__ Xq,
    const u8* __restrict__ Wq,
    const float* __restrict__ b1,
    u8* __restrict__ Z1)
{
    __shared__ u8 Bq[3 * WPL];          // 40,704 B

    const int tid  = threadIdx.x;
    const int lane = tid & 63;
    const int w    = tid >> 6;          // wave 0..3: rows w*32..+32
    // XCD grouping: consecutive logical blocks (same b-tile, all 16 n-slices)
    // land on one XCD: l = (bid%8)*64 + bid/8 ; bt = l>>4 ; ns = l&15
    const int bid = blockIdx.x;
    const int l   = (bid & 7) * 64 + (bid >> 3);
    const int b0  = (l >> 4) * 128;
    const int n0  = (l & 15) * 16;
    const int ls  = lane >> 4;          // k-slice 0..3 (16 B each)
    const int lr  = lane & 15;

    // ---- W -> LDS via regs (padded row stride 848 -> only 2-way aliasing) ----
    #pragma unroll
    for (int it = 0; it < 10; ++it) {
        const int u = it * 256 + tid;                 // 3*16*52 = 2496 units
        if (u < 2496) {
            const int plane = u / 832;
            const int rem   = u - plane * 832;
            const int row   = rem / 52;               // col within slice
            const int sp    = rem - row * 52;         // 16B slot
            const uint4 v = *reinterpret_cast<const uint4*>(
                Wq + (size_t)plane * WPLANE + (size_t)(n0 + row) * KP8 + sp * 16);
            *reinterpret_cast<uint4*>(&Bq[plane * WPL + row * WROW + sp * 16]) = v;
        }
    }
    __syncthreads();                    // the only barrier

    const float bb = b1[n0 + lr];
    float vS[8], cS[8];                 // LIF state per (i,q) = i*4+q
    #pragma unroll
    for (int k = 0; k < 8; ++k) { vS[k] = 0.0f; cS[k] = 0.0f; }

    int bO[3];
    #pragma unroll
    for (int p = 0; p < 3; ++p) bO[p] = p * WPL + lr * WROW + (ls << 4);

    const u8* aP0 = Xq + (size_t)(b0 + w * 32 + lr) * KP8 + ls * 16;  // frag i=0
    const u8* aP1 = aP0 + 16 * KP8;                                    // frag i=1
    const size_t TSTR = (size_t)B_SZ * KP8;

    const float s1 = 4.8828125e-4f;          // 2^-11
    const float s2 = 3.814697265625e-6f;     // 2^-18
    const float s3 = 2.9802322387695312e-8f; // 2^-25

    for (int t = 0; t < T_STEPS; ++t) {
        i32x4 acc[2][3];
        #pragma unroll
        for (int i = 0; i < 2; ++i)
            #pragma unroll
            for (int p = 0; p < 3; ++p)
                acc[i][p] = (i32x4){0, 0, 0, 0};

        uint4 ab[2][2];
        ab[0][0] = *reinterpret_cast<const uint4*>(aP0);
        ab[0][1] = *reinterpret_cast<const uint4*>(aP1);

        #pragma unroll
        for (int s = 0; s < 13; ++s) {
            const int cb = s & 1;
            if (s < 12) {               // ping-pong prefetch next k-step
                ab[cb ^ 1][0] = *reinterpret_cast<const uint4*>(aP0 + (s + 1) * 64);
                ab[cb ^ 1][1] = *reinterpret_cast<const uint4*>(aP1 + (s + 1) * 64);
            }
            uint4 bf[3];
            #pragma unroll
            for (int p = 0; p < 3; ++p)
                bf[p] = *reinterpret_cast<const uint4*>(&Bq[bO[p] + s * 64]);
            #pragma unroll
            for (int i = 0; i < 2; ++i)
                #pragma unroll
                for (int p = 0; p < 3; ++p)
                    acc[i][p] = __builtin_amdgcn_mfma_i32_16x16x64_i8(
                        __builtin_bit_cast(i32x4, ab[cb][i]),
                        __builtin_bit_cast(i32x4, bf[p]),
                        acc[i][p], 0, 0, 0);
        }
        aP0 += TSTR; aP1 += TSTR;       // advance to next t (prefetchable)

        // LIF step in registers; write spikes as i8 (round-8 epilogue math)
        #pragma unroll
        for (int i = 0; i < 2; ++i) {
            #pragma unroll
            for (int q = 0; q < 4; ++q) {
                const int k = i * 4 + q;
                const float c1 = fmaf(s1, (float)acc[i][0][q],
                                 fmaf(s2, (float)acc[i][1][q],
                                 fmaf(s3, (float)acc[i][2][q], bb)));
                const float vd = vS[k] + 0.1f * ((0.0f - vS[k]) + cS[k]);
                const float id = cS[k] - 0.2f * cS[k];
                const bool  sp = vd > 1.0f;
                Z1[(size_t)(t * B_SZ + b0 + w * 32 + i * 16 + ls * 4 + q) * N_HID
                   + n0 + lr] = sp ? (u8)1 : (u8)0;
                vS[k] = sp ? 0.0f : vd;
                cS[k] = id + c1;
            }
        }
    }
}

// ---------------- GEMM2: z1 i8 -> fp32 (exact), K=256, N=10 ----------------
__global__ __launch_bounds__(640) void gemm2_f32(
    const u8* __restrict__ Z, const float* __restrict__ W2,
    const float* __restrict__ b2, float* __restrict__ C2)
{
    __shared__ float zs[64 * 268];
    __shared__ float ws[N_OUT * N_HID];
    const int tid = threadIdx.x;
    const int m0 = blockIdx.x * 64;

    for (int c = tid; c < 1024; c += 640) {          // 64 rows x 16 chunks
        const int r = c >> 4;
        const int col = (c & 15) * 16;
        const uint4 v = *reinterpret_cast<const uint4*>(
            Z + (size_t)(m0 + r) * N_HID + col);
        float* d = &zs[r * 268 + col];
        const u32 wd[4] = {v.x, v.y, v.z, v.w};
        #pragma unroll
        for (int k = 0; k < 4; ++k)
            #pragma unroll
            for (int b = 0; b < 4; ++b)
                d[k * 4 + b] = (float)((wd[k] >> (8 * b)) & 0xffu);
    }
    *(float4*)&ws[tid * 4] = *(const float4*)&W2[tid * 4];
    __syncthreads();

    const int o = tid >> 6;
    const int r = tid & 63;
    float acc = b2[o];
    #pragma unroll
    for (int k = 0; k < N_HID; k += 4) {
        const float4 z4 = *(const float4*)&zs[r * 268 + k];
        const float4 w4 = *(const float4*)&ws[o * N_HID + k];
        acc += z4.x * w4.x + z4.y * w4.y + z4.z * w4.z + z4.w * w4.w;
    }
    C2[(size_t)(m0 + r) * N_OUT + o] = acc;
}

// ---------------- LIF2: per (b,o), loop t; accumulate spike count ----------
__global__ __launch_bounds__(256) void lif2_kernel(
    const float* __restrict__ C2, float* __restrict__ out)
{
    const int g = blockIdx.x * 256 + threadIdx.x;
    const int stride = B_SZ * N_OUT;
    float v = 0.0f, cur = 0.0f, s = 0.0f;
    #pragma unroll
    for (int t = 0; t < T_STEPS; ++t) {
        const float c = C2[t * stride + g];
        const float vd = v + 0.1f * ((0.0f - v) + cur);
        const float id = cur - 0.2f * cur;
        const bool  sp = vd > 1.0f;
        s += sp ? 1.0f : 0.0f;
        v = sp ? 0.0f : vd;
        cur = id + c;
    }
    out[g] = s;
}

extern "C" void kernel_launch(void* const* d_in, const int* in_sizes, int n_in,
                              void* d_out, int out_size, void* d_ws, size_t ws_size,
                              hipStream_t stream)
{
    const float* X  = (const float*)d_in[0];
    const float* W1 = (const float*)d_in[1];
    const float* b1 = (const float*)d_in[2];
    const float* W2 = (const float*)d_in[3];
    const float* b2 = (const float*)d_in[4];
    float* out = (float*)d_out;

    // ws: [Wq 0.64MB | pad->1MB][Xq 54.5MB][Z1 16.8MB][C2 2.6MB]
    char* Wq = (char*)d_ws;
    u8*   Xq = (u8*)d_ws + (1 << 20);
    u8*   Z1 = Xq + (size_t)M_TOT * KP8;
    float* C2 = (float*)(Z1 + (size_t)M_TOT * N_HID);

    conv_x<<<(M_TOT * (KP8 / 16)) / 256, 256, 0, stream>>>(X, Xq);

    conv_w3<<<(N_HID * KP8) / 256, 256, 0, stream>>>(W1, Wq);

    gemm1_lif1<<<512, 256, 0, stream>>>(Xq, (const u8*)Wq, b1, Z1);

    gemm2_f32<<<M_TOT / 64, 640, 0, stream>>>(Z1, W2, b2, C2);

    lif2_kernel<<<(B_SZ * N_OUT) / 256, 256, 0, stream>>>(C2, out);
}